// Round 3
// baseline (363.860 us; speedup 1.0000x reference)
//
#include <hip/hip_runtime.h>
#include <hip/hip_bf16.h>
#include <math.h>

// ---------------------------------------------------------------------------
// GAT 2-layer forward. CSR aggregation, bf16 gather table, inline attention
// weights. bf16 MFMA GEMM (W staged in LDS, XOR-swizzled) + ATOMIC-FREE
// degree histogram (LDS-privatized partials, coalesced non-atomic flush):
//
//   0) init_ws: W1/W2 -> bf16 workspace copies; zero Z
//   1) gemm_mfma<128>: blocks[0,64) = hist: 8 dst-partitions x 8 stripes,
//      25KB LDS private hist each, flush to partial[g][node] (no atomics).
//      blocks[64,64+ntiles) = MFMA gemm1 (bf16 W staged to LDS once/block).
//   2) scan_blocks (sums 8 partials), 3) scan_finish (rowptr; cursor copy)
//   4) scatter_z: blocks[0,256)=z1 edge-parallel; rest dst-partitioned scatter
//   5) csr_aggregate -> x2 (self-loop term inline; relu fused)
//   6) gemm_mfma<64> grid=ntiles (pure gemm2)
//   7) z_edge -> Z[2..3]
//   8) csr_aggregate -> out
//
// MFMA layout (HW-verified m89): A: lane holds A[l&15][(l>>4)*8+j];
// B: B[(l>>4)*8+j][l&15]; D: row=(l>>4)*4+reg, col=l&15.
// LDS swizzle: W row r, 16B-chunk c stored at chunk position c ^ (r & CPR-1).
// ---------------------------------------------------------------------------

#define NHISTB 64        // 8 partitions x 8 stripes
#define HP 8             // dst partitions
#define HRANGE_MAX 6272  // compile-time LDS bound for one partition's counters
#define NZ    256
#define NSCAT 1792       // 8*224

using short8 = __attribute__((ext_vector_type(8))) short;
using f32x4  = __attribute__((ext_vector_type(4))) float;

__device__ __forceinline__ unsigned f2bf(float x) {  // fp32 -> bf16 (RNE)
  unsigned u = __float_as_uint(x);
  return (u + 0x7fffu + ((u >> 16) & 1u)) >> 16;
}
__device__ __forceinline__ float bflo(unsigned p) { return __uint_as_float(p << 16); }
__device__ __forceinline__ float bfhi(unsigned p) { return __uint_as_float(p & 0xffff0000u); }

// W -> bf16 copies + zero Z (cursor zeroing no longer needed: scan_finish
// fully overwrites cursor before the scatter uses it)
__global__ __launch_bounds__(256) void init_ws(
    const float* __restrict__ W1, const float* __restrict__ W2,
    unsigned short* __restrict__ wbf1, unsigned short* __restrict__ wbf2,
    float* __restrict__ Z) {
  int tid = blockIdx.x * 256 + threadIdx.x;
  int stride = gridDim.x * 256;
  for (int i = tid; i < 128 * 128; i += stride)
    wbf1[i] = (unsigned short)f2bf(W1[i]);
  for (int i = tid; i < 128 * 64; i += stride)
    wbf2[i] = (unsigned short)f2bf(W2[i]);
  if (tid < 4) Z[tid] = 0.f;
}

// MFMA GEMM (h = x @ W^T) + fused attention scores + bf16 pack.
// blocks < nhistb run the atomic-free LDS-privatized degree histogram.
template <int FIN>
__global__ __launch_bounds__(256) void gemm_mfma(
    const float* __restrict__ x, const unsigned short* __restrict__ Wb,
    const float* __restrict__ att, unsigned* __restrict__ hq,
    float* __restrict__ si, float* __restrict__ sj,
    int N,
    const int* __restrict__ dstE, int* __restrict__ partial,
    int E, int nhistb, int hstep) {
  const int tid = threadIdx.x;

  constexpr int WB = 128 * FIN * 2;  // bf16 W tile bytes
  constexpr int SMEM = (WB > HRANGE_MAX * 4) ? WB : HRANGE_MAX * 4;
  __shared__ __align__(16) unsigned char smem[SMEM];

  if ((int)blockIdx.x < nhistb) {
    // ---- atomic-free histogram: partition p, stripe g ----
    int* lhist = (int*)smem;
    const int p = blockIdx.x & (HP - 1);
    const int g = blockIdx.x >> 3;        // 8 stripes
    const int lo = p * hstep;
    for (int i = tid; i < hstep; i += 256) lhist[i] = 0;
    __syncthreads();
    for (int e = g * 256 + tid; e < E; e += 8 * 256) {
      int d = dstE[e] - lo;
      if ((unsigned)d < (unsigned)hstep) atomicAdd(&lhist[d], 1);  // LDS atomic
    }
    __syncthreads();
    for (int i = tid; i < hstep; i += 256) {
      int node = lo + i;
      if (node < N) partial[(size_t)g * N + node] = lhist[i];
    }
    return;
  }

  constexpr int KS = FIN / 32;        // k-steps of 32
  constexpr int CPR = FIN / 8;        // 16B chunks per W row
  constexpr int NCHUNK = 128 * CPR;   // total 16B chunks (128 out-cols)

  unsigned short* wlds = (unsigned short*)smem;  // bf16 W, swizzled

  const int w    = tid >> 6;    // wave 0..3 -> rows [w*16, w*16+16)
  const int lane = tid & 63;
  const int cl   = lane & 15;   // A-row / D-col within tile
  const int grp  = lane >> 4;   // k-group / D-row-group
  const int n0   = (blockIdx.x - nhistb) * 64;

  // ---- issue A loads early (fp32 x, 8 contiguous floats per ks) ----
  const int arow = n0 + w * 16 + cl;
  const bool avalid = arow < N;
  float4 av0[KS], av1[KS];
#pragma unroll
  for (int ks = 0; ks < KS; ++ks) {
    av0[ks] = make_float4(0.f, 0.f, 0.f, 0.f);
    av1[ks] = av0[ks];
    if (avalid) {
      const float4* xp =
          (const float4*)(x + (size_t)arow * FIN + ks * 32 + grp * 8);
      av0[ks] = xp[0];
      av1[ks] = xp[1];
    }
  }

  // ---- stage bf16 W -> LDS, XOR-swizzled 16B chunks ----
  const uint4* Wb4 = (const uint4*)Wb;
  for (int c = tid; c < NCHUNK; c += 256) {
    int row = c / CPR;           // CPR is pow2 -> shift
    int cc  = c & (CPR - 1);
    *(uint4*)&wlds[row * FIN + ((cc ^ (row & (CPR - 1))) * 8)] = Wb4[c];
  }
  __syncthreads();

  // ---- convert A to bf16 fragments ----
  short8 afrag[KS];
#pragma unroll
  for (int ks = 0; ks < KS; ++ks) {
    union { short8 s8; unsigned u[4]; } af;
    af.u[0] = f2bf(av0[ks].x) | (f2bf(av0[ks].y) << 16);
    af.u[1] = f2bf(av0[ks].z) | (f2bf(av0[ks].w) << 16);
    af.u[2] = f2bf(av1[ks].x) | (f2bf(av1[ks].y) << 16);
    af.u[3] = f2bf(av1[ks].z) | (f2bf(av1[ks].w) << 16);
    afrag[ks] = af.s8;
  }

  // ---- MFMA main: 8 col-tiles x KS k-steps; B-frags from LDS ----
  f32x4 acc[8];
#pragma unroll
  for (int ct = 0; ct < 8; ++ct) acc[ct] = (f32x4){0.f, 0.f, 0.f, 0.f};

  const int swz = cl & (CPR - 1);  // (ct*16+cl) & (CPR-1) == cl & (CPR-1)
#pragma unroll
  for (int ks = 0; ks < KS; ++ks) {
#pragma unroll
    for (int ct = 0; ct < 8; ++ct) {
      const unsigned short* bp =
          &wlds[(ct * 16 + cl) * FIN + (((ks * 4 + grp) ^ swz) * 8)];
      short8 bfrag = *(const short8*)bp;
      acc[ct] = __builtin_amdgcn_mfma_f32_16x16x32_bf16(afrag[ks], bfrag,
                                                        acc[ct], 0, 0, 0);
    }
  }

  // ---- epilogue: fused attention scores + packed bf16x2 h ----
  // lane's cols: head0 -> ct*16+cl (ct 0..3), head1 -> (ct-4)*16+cl (ct 4..7)
  float ai[8], aj[8];
#pragma unroll
  for (int ct = 0; ct < 8; ++ct) {
    int hd = ct >> 2;
    int cw = (ct & 3) * 16 + cl;
    ai[ct] = att[hd * 128 + cw];
    aj[ct] = att[hd * 128 + 64 + cw];
  }

#pragma unroll
  for (int r = 0; r < 4; ++r) {
    int node = n0 + w * 16 + grp * 4 + r;  // D row for this reg
    float s0i = 0.f, s0j = 0.f, s1i = 0.f, s1j = 0.f;
    unsigned wpk[4];
#pragma unroll
    for (int ct = 0; ct < 4; ++ct) {
      float v0 = acc[ct][r];      // head0, col ct*16+cl
      float v1 = acc[ct + 4][r];  // head1, same channel
      s0i += v0 * ai[ct];
      s0j += v0 * aj[ct];
      s1i += v1 * ai[ct + 4];
      s1j += v1 * aj[ct + 4];
      wpk[ct] = f2bf(v0) | (f2bf(v1) << 16);
    }
    // reduce the 16 channel-lanes of this group
#pragma unroll
    for (int off = 8; off; off >>= 1) {
      s0i += __shfl_xor(s0i, off, 64);
      s0j += __shfl_xor(s0j, off, 64);
      s1i += __shfl_xor(s1i, off, 64);
      s1j += __shfl_xor(s1j, off, 64);
    }
    if (node < N) {
#pragma unroll
      for (int ct = 0; ct < 4; ++ct)
        hq[(size_t)node * 64 + ct * 16 + cl] = wpk[ct];
      if (cl == 0) {
        si[node * 2 + 0] = s0i;
        si[node * 2 + 1] = s1i;
        sj[node * 2 + 0] = s0j;
        sj[node * 2 + 1] = s1j;
      }
    }
  }
}

// edge-parallel Z sum over the ORIGINAL edge list incl. self-loops
__device__ __forceinline__ void z_edge_body(
    const int* __restrict__ srcE, const int* __restrict__ dstE,
    const float2* __restrict__ si2, const float2* __restrict__ sj2,
    float* __restrict__ Zp, int E, int Etot, int tid0, int stride) {
  float z0 = 0.f, z1 = 0.f;
  for (int e = tid0; e < Etot; e += stride) {
    int s, d;
    if (e < E) { s = srcE[e]; d = dstE[e]; } else { s = d = e - E; }
    float2 siv = si2[d];
    float2 sjv = sj2[s];
    float a0 = siv.x + sjv.x;
    float a1 = siv.y + sjv.y;
    a0 = a0 >= 0.f ? a0 : 0.2f * a0;
    a1 = a1 >= 0.f ? a1 : 0.2f * a1;
    z0 += __expf(a0); z1 += __expf(a1);
  }
  __shared__ float r0[4], r1[4];
  int lane = threadIdx.x & 63, w = threadIdx.x >> 6;
#pragma unroll
  for (int off = 32; off; off >>= 1) {
    z0 += __shfl_down(z0, off, 64);
    z1 += __shfl_down(z1, off, 64);
  }
  if (lane == 0) { r0[w] = z0; r1[w] = z1; }
  __syncthreads();
  if (threadIdx.x == 0) {
    atomicAdd(&Zp[0], r0[0] + r0[1] + r0[2] + r0[3]);
    atomicAdd(&Zp[1], r1[0] + r1[1] + r1[2] + r1[3]);
  }
}

__global__ __launch_bounds__(256) void z_edge(
    const int* __restrict__ srcE, const int* __restrict__ dstE,
    const float2* __restrict__ si2, const float2* __restrict__ sj2,
    float* __restrict__ Zp, int E, int Etot) {
  z_edge_body(srcE, dstE, si2, sj2, Zp, E, Etot,
              blockIdx.x * 256 + threadIdx.x, gridDim.x * 256);
}

// rowptr prefix over per-stripe partials (sums NHISTB/HP = 8 stripes)
__global__ __launch_bounds__(256) void scan_blocks(
    const int* __restrict__ partial, int* __restrict__ rowptr,
    int* __restrict__ bsum, int N) {
  __shared__ int ts[256];
  int b = blockIdx.x, t = threadIdx.x;
  int base = b * 1024 + t * 4;
  int v[4];
#pragma unroll
  for (int j = 0; j < 4; ++j) {
    v[j] = 0;
    if (base + j < N) {
#pragma unroll
      for (int g = 0; g < 8; ++g) v[j] += partial[(size_t)g * N + base + j];
    }
  }
  int tot = v[0] + v[1] + v[2] + v[3];
  ts[t] = tot;
  __syncthreads();
#pragma unroll
  for (int off = 1; off < 256; off <<= 1) {
    int x = (t >= off) ? ts[t - off] : 0;
    __syncthreads();
    ts[t] += x;
    __syncthreads();
  }
  int run = ts[t] - tot;
#pragma unroll
  for (int j = 0; j < 4; ++j) {
    if (base + j < N) rowptr[base + j] = run;
    run += v[j];
  }
  if (t == 255) bsum[b] = ts[255];
}

// folds the bsum scan in: serial prefix of bsum (nb<=256) in LDS per block
__global__ __launch_bounds__(256) void scan_finish(
    int* __restrict__ rowptr, const int* __restrict__ bsum,
    int* __restrict__ cursor, int N, int Eall, int nb) {
  __shared__ int pre[256];
  if (threadIdx.x == 0) {
    int run = 0;
    for (int i = 0; i < nb; ++i) { pre[i] = run; run += bsum[i]; }
  }
  __syncthreads();
  int tid = blockIdx.x * blockDim.x + threadIdx.x;
  int stride = gridDim.x * blockDim.x;
  for (int i = tid; i < N; i += stride) {
    int v = rowptr[i] + pre[i >> 10];
    rowptr[i] = v;
    cursor[i] = v;
  }
  if (tid == 0) rowptr[N] = Eall;
}

// blocks[0,NZ): z1 edge-parallel (dispatched FIRST -> co-schedules under
// the scatter); blocks[NZ,NZ+NSCAT): dst-partitioned scatter (%8 affine).
__global__ __launch_bounds__(256) void scatter_z(
    const int* __restrict__ srcE, const int* __restrict__ dstE,
    int* __restrict__ cursor, int* __restrict__ esrc,
    const float2* __restrict__ si2, const float2* __restrict__ sj2,
    float* __restrict__ Zp, int E, int Etot, int step) {
  if ((int)blockIdx.x < NZ) {
    z_edge_body(srcE, dstE, si2, sj2, Zp, E, Etot,
                blockIdx.x * 256 + threadIdx.x, NZ * 256);
    return;
  }
  const int bid = blockIdx.x - NZ;
  const int p = bid & 7;
  const int sub = bid >> 3;
  const int nsub = NSCAT >> 3;
  const int lo = p * step;
  const int hi = lo + step;
  int stride = nsub * 256;
  for (int e = sub * 256 + threadIdx.x; e < E; e += stride) {
    int d = dstE[e];
    if (d >= lo && d < hi) {
      int s = srcE[e];
      int pos = atomicAdd(&cursor[d], 1);
      esrc[pos] = s;
    }
  }
}

// one wave per dst node (scalarized): inline attention weights, inline
// self-loop term, acc += w * hq[src], fused head-mean + bias (+relu)
__global__ __launch_bounds__(256) void csr_aggregate(
    const int* __restrict__ rowptr, const int* __restrict__ esrc,
    const unsigned* __restrict__ hq, const float2* __restrict__ si2,
    const float2* __restrict__ sj2, const float* __restrict__ Zp,
    const float* __restrict__ bias, float* __restrict__ out,
    int N, int do_relu) {
  int lane = threadIdx.x & 63;
  int wid = (blockIdx.x * blockDim.x + threadIdx.x) >> 6;
  int nw = (gridDim.x * blockDim.x) >> 6;
  float z0 = 1.f / (Zp[0] + 1e-10f);
  float z1 = 1.f / (Zp[1] + 1e-10f);
  float bv = bias[lane];
  for (int n0 = wid; n0 < N; n0 += nw) {
    // n is wave-uniform; force SGPR so the rowptr/esrc/sj2 chain is scalar
    int n = __builtin_amdgcn_readfirstlane(n0);
    int beg = rowptr[n], end = rowptr[n + 1];
    float2 siv = si2[n];
    // self-loop term (src = dst = n)
    float acc0, acc1;
    {
      float2 jv = sj2[n];
      unsigned p = hq[(size_t)n * 64 + lane];
      float a0 = siv.x + jv.x, a1 = siv.y + jv.y;
      a0 = a0 >= 0.f ? a0 : 0.2f * a0;
      a1 = a1 >= 0.f ? a1 : 0.2f * a1;
      acc0 = bflo(p) * __expf(a0);
      acc1 = bfhi(p) * __expf(a1);
    }
    int k = beg;
    for (; k + 4 <= end; k += 4) {
      int s0 = esrc[k], s1 = esrc[k + 1], s2 = esrc[k + 2], s3 = esrc[k + 3];
      float2 j0 = sj2[s0], j1 = sj2[s1], j2 = sj2[s2], j3 = sj2[s3];
      unsigned p0 = hq[(size_t)s0 * 64 + lane];
      unsigned p1 = hq[(size_t)s1 * 64 + lane];
      unsigned p2 = hq[(size_t)s2 * 64 + lane];
      unsigned p3 = hq[(size_t)s3 * 64 + lane];
      float a00 = siv.x + j0.x, a01 = siv.y + j0.y;
      float a10 = siv.x + j1.x, a11 = siv.y + j1.y;
      float a20 = siv.x + j2.x, a21 = siv.y + j2.y;
      float a30 = siv.x + j3.x, a31 = siv.y + j3.y;
      a00 = a00 >= 0.f ? a00 : 0.2f * a00;  a01 = a01 >= 0.f ? a01 : 0.2f * a01;
      a10 = a10 >= 0.f ? a10 : 0.2f * a10;  a11 = a11 >= 0.f ? a11 : 0.2f * a11;
      a20 = a20 >= 0.f ? a20 : 0.2f * a20;  a21 = a21 >= 0.f ? a21 : 0.2f * a21;
      a30 = a30 >= 0.f ? a30 : 0.2f * a30;  a31 = a31 >= 0.f ? a31 : 0.2f * a31;
      float w00 = __expf(a00), w01 = __expf(a01);
      float w10 = __expf(a10), w11 = __expf(a11);
      float w20 = __expf(a20), w21 = __expf(a21);
      float w30 = __expf(a30), w31 = __expf(a31);
      acc0 += bflo(p0) * w00 + bflo(p1) * w10 + bflo(p2) * w20 + bflo(p3) * w30;
      acc1 += bfhi(p0) * w01 + bfhi(p1) * w11 + bfhi(p2) * w21 + bfhi(p3) * w31;
    }
    for (; k < end; ++k) {
      int s = esrc[k];
      float2 jv = sj2[s];
      unsigned p = hq[(size_t)s * 64 + lane];
      float a0 = siv.x + jv.x, a1 = siv.y + jv.y;
      a0 = a0 >= 0.f ? a0 : 0.2f * a0;
      a1 = a1 >= 0.f ? a1 : 0.2f * a1;
      acc0 += bflo(p) * __expf(a0);
      acc1 += bfhi(p) * __expf(a1);
    }
    float r = 0.5f * (acc0 * z0 + acc1 * z1) + bv;
    if (do_relu) r = fmaxf(r, 0.f);
    out[(size_t)n * 64 + lane] = r;
  }
}

extern "C" void kernel_launch(void* const* d_in, const int* in_sizes, int n_in,
                              void* d_out, int out_size, void* d_ws, size_t ws_size,
                              hipStream_t stream) {
  const float* x    = (const float*)d_in[0];
  const int*   ei   = (const int*)d_in[1];   // [2, E] int32
  const float* W1   = (const float*)d_in[2];
  const float* att1 = (const float*)d_in[3];
  const float* b1   = (const float*)d_in[4];
  const float* W2   = (const float*)d_in[5];
  const float* att2 = (const float*)d_in[6];
  const float* b2   = (const float*)d_in[7];
  float* out = (float*)d_out;

  const int N = in_sizes[0] / 128;   // 50000
  const int E = in_sizes[1] / 2;     // 800000
  const int Etot = E + N;            // incl. self-loops (Z sums only)
  const int* srcE = ei;
  const int* dstE = ei + E;

  // workspace layout (16B-sensitive arrays aligned)
  unsigned* hq = (unsigned*)d_ws;                 // N*64 packed bf16x2
  float* si    = (float*)(hq + (size_t)N * 64);   // N*2
  float* sj    = si + (size_t)N * 2;              // N*2
  float* Z     = sj + (size_t)N * 2;              // 4 (L1: Z[0..1], L2: Z[2..3])
  float* x2    = Z + 4;                           // N*64
  int* rowptr  = (int*)(x2 + (size_t)N * 64);     // N+1
  int* cursor  = rowptr + (N + 1);                // N
  int* esrc    = cursor + N;                      // E (real edges only)
  int* bsum    = esrc + E;                        // up to 256
  uintptr_t wp = ((uintptr_t)(bsum + 256) + 15) & ~(uintptr_t)15;
  unsigned short* wbf1 = (unsigned short*)wp;     // 128*128 bf16 W1
  unsigned short* wbf2 = wbf1 + 128 * 128;        // 128*64 bf16 W2
  int* partial = (int*)(wbf2 + 128 * 64);         // 8*N stripe histograms

  dim3 blk(256);
  int nb = (N + 1023) / 1024;
  int ntiles = (N + 63) / 64;
  int step = (N + 7) / 8;       // scatter partition width
  int hstep = (N + HP - 1) / HP;  // hist partition width (6250 <= HRANGE_MAX)

  // 0) W -> bf16 + zero Z
  init_ws<<<64, blk, 0, stream>>>(W1, W2, wbf1, wbf2, Z);
  // 1) hist (blocks[0,64), atomic-free) + gemm1 (MFMA, LDS-staged bf16 W)
  gemm_mfma<128><<<NHISTB + ntiles, blk, 0, stream>>>(
      x, wbf1, att1, hq, si, sj, N, dstE, partial, E, NHISTB, hstep);
  // 2,3) rowptr prefix (sums stripe partials)
  scan_blocks<<<nb, blk, 0, stream>>>(partial, rowptr, bsum, N);
  scan_finish<<<256, blk, 0, stream>>>(rowptr, bsum, cursor, N, E, nb);
  // 4) z1 (first 256 blocks, co-scheduled) + scatter (1792 blocks)
  scatter_z<<<NZ + NSCAT, blk, 0, stream>>>(
      srcE, dstE, cursor, esrc, (const float2*)si, (const float2*)sj,
      Z, E, Etot, step);
  // 5) layer-1 aggregation -> x2 (self-loop inline; relu fused)
  csr_aggregate<<<4096, blk, 0, stream>>>(rowptr, esrc, hq, (const float2*)si,
                                          (const float2*)sj, Z, b1, x2, N, 1);
  // 6) gemm2 (MFMA, nhistb=0: hist branch never taken)
  gemm_mfma<64><<<ntiles, blk, 0, stream>>>(
      x2, wbf2, att2, hq, si, sj, N, dstE, partial, E, 0, hstep);
  // 7) z2
  z_edge<<<NZ, blk, 0, stream>>>(srcE, dstE, (const float2*)si,
                                 (const float2*)sj, Z + 2, E, Etot);
  // 8) layer-2 aggregation -> out
  csr_aggregate<<<4096, blk, 0, stream>>>(rowptr, esrc, hq, (const float2*)si,
                                          (const float2*)sj, Z + 2, b2, out, N, 0);
}

// Round 4
// 261.527 us; speedup vs baseline: 1.3913x; 1.3913x over previous
//
#include <hip/hip_runtime.h>
#include <hip/hip_bf16.h>
#include <math.h>

// ---------------------------------------------------------------------------
// GAT 2-layer forward. CSR aggregation, bf16 gather table, inline attention
// weights. bf16 MFMA GEMM (W staged in LDS, XOR-swizzled). CSR build is
// FULLY ATOMIC-FREE (global): per-(partition,stripe) LDS histograms ->
// exclusive per-stripe offsets -> LDS-cursor placement.
//
//   0) init_ws: W1/W2 -> bf16 workspace copies; zero Z
//   1) gemm_mfma<128>: blocks[0,512) = hist: 8 dst-partitions x 64 edge-
//      stripes, 25KB LDS private hist, flush partial[g][node] (non-atomic).
//      blocks[512,512+ntiles) = MFMA gemm1 (bf16 W staged to LDS).
//   2) reduce_deg: deg[n] = sum_g partial[g][n]  (wide-parallel)
//   3) scan_blocks, 4) scan_finish: rowptr prefix + convert partial[g][n]
//      into exclusive placement offsets (rowptr[n] + sum_{g'<g} cnt)
//   5) scatter_z: blocks[0,256)=z1; blocks[256,256+512)= atomic-free scatter
//      (same (p,g) mapping; LDS cursor initialized from partial offsets)
//   6) csr_aggregate -> x2 (self-loop inline; relu fused)   [x2 overlays partial]
//   7) gemm_mfma<64> grid=ntiles (pure gemm2)
//   8) z_edge -> Z[2..3]
//   9) csr_aggregate -> out
//
// MFMA layout (HW-verified m89): A: lane holds A[l&15][(l>>4)*8+j];
// B: B[(l>>4)*8+j][l&15]; D: row=(l>>4)*4+reg, col=l&15.
// LDS swizzle: W row r, 16B-chunk c stored at chunk position c ^ (r & CPR-1).
// ---------------------------------------------------------------------------

#define HP 8             // dst partitions
#define HG 64            // edge stripes
#define NHISTB (HP * HG) // 512 hist/scatter blocks
#define HRANGE_MAX 6272  // compile-time LDS bound for one partition's counters
#define NZ    256

using short8 = __attribute__((ext_vector_type(8))) short;
using f32x4  = __attribute__((ext_vector_type(4))) float;

__device__ __forceinline__ unsigned f2bf(float x) {  // fp32 -> bf16 (RNE)
  unsigned u = __float_as_uint(x);
  return (u + 0x7fffu + ((u >> 16) & 1u)) >> 16;
}
__device__ __forceinline__ float bflo(unsigned p) { return __uint_as_float(p << 16); }
__device__ __forceinline__ float bfhi(unsigned p) { return __uint_as_float(p & 0xffff0000u); }

// W -> bf16 copies + zero Z
__global__ __launch_bounds__(256) void init_ws(
    const float* __restrict__ W1, const float* __restrict__ W2,
    unsigned short* __restrict__ wbf1, unsigned short* __restrict__ wbf2,
    float* __restrict__ Z) {
  int tid = blockIdx.x * 256 + threadIdx.x;
  int stride = gridDim.x * 256;
  for (int i = tid; i < 128 * 128; i += stride)
    wbf1[i] = (unsigned short)f2bf(W1[i]);
  for (int i = tid; i < 128 * 64; i += stride)
    wbf2[i] = (unsigned short)f2bf(W2[i]);
  if (tid < 4) Z[tid] = 0.f;
}

// MFMA GEMM (h = x @ W^T) + fused attention scores + bf16 pack.
// blocks < nhistb run the atomic-free LDS-privatized degree histogram.
template <int FIN>
__global__ __launch_bounds__(256) void gemm_mfma(
    const float* __restrict__ x, const unsigned short* __restrict__ Wb,
    const float* __restrict__ att, unsigned* __restrict__ hq,
    float* __restrict__ si, float* __restrict__ sj,
    int N,
    const int* __restrict__ dstE, int* __restrict__ partial,
    int E, int nhistb, int hstep) {
  const int tid = threadIdx.x;

  constexpr int WB = 128 * FIN * 2;  // bf16 W tile bytes
  constexpr int SMEM = (WB > HRANGE_MAX * 4) ? WB : HRANGE_MAX * 4;
  __shared__ __align__(16) unsigned char smem[SMEM];

  if ((int)blockIdx.x < nhistb) {
    // ---- atomic-free histogram: partition p, stripe g ----
    int* lhist = (int*)smem;
    const int p = blockIdx.x & (HP - 1);
    const int g = blockIdx.x >> 3;        // stripe 0..HG-1
    const int lo = p * hstep;
    for (int i = tid; i < hstep; i += 256) lhist[i] = 0;
    __syncthreads();
    const int stride = HG * 256;
    int e = g * 256 + tid;
    for (; e + 3 * stride < E; e += 4 * stride) {
      int d0 = dstE[e] - lo;
      int d1 = dstE[e + stride] - lo;
      int d2 = dstE[e + 2 * stride] - lo;
      int d3 = dstE[e + 3 * stride] - lo;
      if ((unsigned)d0 < (unsigned)hstep) atomicAdd(&lhist[d0], 1);
      if ((unsigned)d1 < (unsigned)hstep) atomicAdd(&lhist[d1], 1);
      if ((unsigned)d2 < (unsigned)hstep) atomicAdd(&lhist[d2], 1);
      if ((unsigned)d3 < (unsigned)hstep) atomicAdd(&lhist[d3], 1);
    }
    for (; e < E; e += stride) {
      int d = dstE[e] - lo;
      if ((unsigned)d < (unsigned)hstep) atomicAdd(&lhist[d], 1);
    }
    __syncthreads();
    for (int i = tid; i < hstep; i += 256) {
      int node = lo + i;
      if (node < N) partial[(size_t)g * N + node] = lhist[i];
    }
    return;
  }

  constexpr int KS = FIN / 32;        // k-steps of 32
  constexpr int CPR = FIN / 8;        // 16B chunks per W row
  constexpr int NCHUNK = 128 * CPR;   // total 16B chunks (128 out-cols)

  unsigned short* wlds = (unsigned short*)smem;  // bf16 W, swizzled

  const int w    = tid >> 6;    // wave 0..3 -> rows [w*16, w*16+16)
  const int lane = tid & 63;
  const int cl   = lane & 15;   // A-row / D-col within tile
  const int grp  = lane >> 4;   // k-group / D-row-group
  const int n0   = (blockIdx.x - nhistb) * 64;

  // ---- issue A loads early (fp32 x, 8 contiguous floats per ks) ----
  const int arow = n0 + w * 16 + cl;
  const bool avalid = arow < N;
  float4 av0[KS], av1[KS];
#pragma unroll
  for (int ks = 0; ks < KS; ++ks) {
    av0[ks] = make_float4(0.f, 0.f, 0.f, 0.f);
    av1[ks] = av0[ks];
    if (avalid) {
      const float4* xp =
          (const float4*)(x + (size_t)arow * FIN + ks * 32 + grp * 8);
      av0[ks] = xp[0];
      av1[ks] = xp[1];
    }
  }

  // ---- stage bf16 W -> LDS, XOR-swizzled 16B chunks ----
  const uint4* Wb4 = (const uint4*)Wb;
  for (int c = tid; c < NCHUNK; c += 256) {
    int row = c / CPR;           // CPR is pow2 -> shift
    int cc  = c & (CPR - 1);
    *(uint4*)&wlds[row * FIN + ((cc ^ (row & (CPR - 1))) * 8)] = Wb4[c];
  }
  __syncthreads();

  // ---- convert A to bf16 fragments ----
  short8 afrag[KS];
#pragma unroll
  for (int ks = 0; ks < KS; ++ks) {
    union { short8 s8; unsigned u[4]; } af;
    af.u[0] = f2bf(av0[ks].x) | (f2bf(av0[ks].y) << 16);
    af.u[1] = f2bf(av0[ks].z) | (f2bf(av0[ks].w) << 16);
    af.u[2] = f2bf(av1[ks].x) | (f2bf(av1[ks].y) << 16);
    af.u[3] = f2bf(av1[ks].z) | (f2bf(av1[ks].w) << 16);
    afrag[ks] = af.s8;
  }

  // ---- MFMA main: 8 col-tiles x KS k-steps; B-frags from LDS ----
  f32x4 acc[8];
#pragma unroll
  for (int ct = 0; ct < 8; ++ct) acc[ct] = (f32x4){0.f, 0.f, 0.f, 0.f};

  const int swz = cl & (CPR - 1);  // (ct*16+cl) & (CPR-1) == cl & (CPR-1)
#pragma unroll
  for (int ks = 0; ks < KS; ++ks) {
#pragma unroll
    for (int ct = 0; ct < 8; ++ct) {
      const unsigned short* bp =
          &wlds[(ct * 16 + cl) * FIN + (((ks * 4 + grp) ^ swz) * 8)];
      short8 bfrag = *(const short8*)bp;
      acc[ct] = __builtin_amdgcn_mfma_f32_16x16x32_bf16(afrag[ks], bfrag,
                                                        acc[ct], 0, 0, 0);
    }
  }

  // ---- epilogue: fused attention scores + packed bf16x2 h ----
  // lane's cols: head0 -> ct*16+cl (ct 0..3), head1 -> (ct-4)*16+cl (ct 4..7)
  float ai[8], aj[8];
#pragma unroll
  for (int ct = 0; ct < 8; ++ct) {
    int hd = ct >> 2;
    int cw = (ct & 3) * 16 + cl;
    ai[ct] = att[hd * 128 + cw];
    aj[ct] = att[hd * 128 + 64 + cw];
  }

#pragma unroll
  for (int r = 0; r < 4; ++r) {
    int node = n0 + w * 16 + grp * 4 + r;  // D row for this reg
    float s0i = 0.f, s0j = 0.f, s1i = 0.f, s1j = 0.f;
    unsigned wpk[4];
#pragma unroll
    for (int ct = 0; ct < 4; ++ct) {
      float v0 = acc[ct][r];      // head0, col ct*16+cl
      float v1 = acc[ct + 4][r];  // head1, same channel
      s0i += v0 * ai[ct];
      s0j += v0 * aj[ct];
      s1i += v1 * ai[ct + 4];
      s1j += v1 * aj[ct + 4];
      wpk[ct] = f2bf(v0) | (f2bf(v1) << 16);
    }
    // reduce the 16 channel-lanes of this group
#pragma unroll
    for (int off = 8; off; off >>= 1) {
      s0i += __shfl_xor(s0i, off, 64);
      s0j += __shfl_xor(s0j, off, 64);
      s1i += __shfl_xor(s1i, off, 64);
      s1j += __shfl_xor(s1j, off, 64);
    }
    if (node < N) {
#pragma unroll
      for (int ct = 0; ct < 4; ++ct)
        hq[(size_t)node * 64 + ct * 16 + cl] = wpk[ct];
      if (cl == 0) {
        si[node * 2 + 0] = s0i;
        si[node * 2 + 1] = s1i;
        sj[node * 2 + 0] = s0j;
        sj[node * 2 + 1] = s1j;
      }
    }
  }
}

// deg[n] = sum over stripes of partial[g][n]  (wide-parallel, coalesced)
__global__ __launch_bounds__(256) void reduce_deg(
    const int* __restrict__ partial, int* __restrict__ deg, int N) {
  int i = blockIdx.x * 256 + threadIdx.x;
  int stride = gridDim.x * 256;
  for (; i < N; i += stride) {
    int s = 0;
#pragma unroll
    for (int g = 0; g < HG; ++g) s += partial[(size_t)g * N + i];
    deg[i] = s;
  }
}

// edge-parallel Z sum over the ORIGINAL edge list incl. self-loops
__device__ __forceinline__ void z_edge_body(
    const int* __restrict__ srcE, const int* __restrict__ dstE,
    const float2* __restrict__ si2, const float2* __restrict__ sj2,
    float* __restrict__ Zp, int E, int Etot, int tid0, int stride) {
  float z0 = 0.f, z1 = 0.f;
  for (int e = tid0; e < Etot; e += stride) {
    int s, d;
    if (e < E) { s = srcE[e]; d = dstE[e]; } else { s = d = e - E; }
    float2 siv = si2[d];
    float2 sjv = sj2[s];
    float a0 = siv.x + sjv.x;
    float a1 = siv.y + sjv.y;
    a0 = a0 >= 0.f ? a0 : 0.2f * a0;
    a1 = a1 >= 0.f ? a1 : 0.2f * a1;
    z0 += __expf(a0); z1 += __expf(a1);
  }
  __shared__ float r0[4], r1[4];
  int lane = threadIdx.x & 63, w = threadIdx.x >> 6;
#pragma unroll
  for (int off = 32; off; off >>= 1) {
    z0 += __shfl_down(z0, off, 64);
    z1 += __shfl_down(z1, off, 64);
  }
  if (lane == 0) { r0[w] = z0; r1[w] = z1; }
  __syncthreads();
  if (threadIdx.x == 0) {
    atomicAdd(&Zp[0], r0[0] + r0[1] + r0[2] + r0[3]);
    atomicAdd(&Zp[1], r1[0] + r1[1] + r1[2] + r1[3]);
  }
}

__global__ __launch_bounds__(256) void z_edge(
    const int* __restrict__ srcE, const int* __restrict__ dstE,
    const float2* __restrict__ si2, const float2* __restrict__ sj2,
    float* __restrict__ Zp, int E, int Etot) {
  z_edge_body(srcE, dstE, si2, sj2, Zp, E, Etot,
              blockIdx.x * 256 + threadIdx.x, gridDim.x * 256);
}

__global__ __launch_bounds__(256) void scan_blocks(
    const int* __restrict__ deg, int* __restrict__ rowptr,
    int* __restrict__ bsum, int N) {
  __shared__ int ts[256];
  int b = blockIdx.x, t = threadIdx.x;
  int base = b * 1024 + t * 4;
  int v[4];
#pragma unroll
  for (int j = 0; j < 4; ++j) v[j] = (base + j < N) ? deg[base + j] : 0;
  int tot = v[0] + v[1] + v[2] + v[3];
  ts[t] = tot;
  __syncthreads();
#pragma unroll
  for (int off = 1; off < 256; off <<= 1) {
    int x = (t >= off) ? ts[t - off] : 0;
    __syncthreads();
    ts[t] += x;
    __syncthreads();
  }
  int run = ts[t] - tot;
#pragma unroll
  for (int j = 0; j < 4; ++j) {
    if (base + j < N) rowptr[base + j] = run;
    run += v[j];
  }
  if (t == 255) bsum[b] = ts[255];
}

// rowptr finalization + per-(stripe,node) exclusive placement offsets:
// partial[g][n] <- rowptr[n] + sum_{g'<g} partial[g'][n]
__global__ __launch_bounds__(256) void scan_finish(
    int* __restrict__ rowptr, const int* __restrict__ bsum,
    int* __restrict__ partial, int N, int Eall, int nb) {
  __shared__ int pre[256];
  if (threadIdx.x == 0) {
    int run = 0;
    for (int i = 0; i < nb; ++i) { pre[i] = run; run += bsum[i]; }
  }
  __syncthreads();
  int tid = blockIdx.x * blockDim.x + threadIdx.x;
  int stride = gridDim.x * blockDim.x;
  for (int i = tid; i < N; i += stride) {
    int v = rowptr[i] + pre[i >> 10];
    rowptr[i] = v;
    int run = v;
#pragma unroll 8
    for (int g = 0; g < HG; ++g) {
      int c = partial[(size_t)g * N + i];
      partial[(size_t)g * N + i] = run;
      run += c;
    }
  }
  if (tid == 0) rowptr[N] = Eall;
}

// blocks[0,NZ): z1 edge-parallel; blocks[NZ,NZ+NHISTB): atomic-free scatter.
// Block (p,g) loads its offset segment into LDS cursors, walks stripe g,
// places in-partition edges at exclusive positions. No global atomics.
__global__ __launch_bounds__(256) void scatter_z(
    const int* __restrict__ srcE, const int* __restrict__ dstE,
    const int* __restrict__ partial, int* __restrict__ esrc,
    const float2* __restrict__ si2, const float2* __restrict__ sj2,
    float* __restrict__ Zp, int E, int Etot, int hstep, int N) {
  __shared__ __align__(16) int lcur[HRANGE_MAX];
  if ((int)blockIdx.x < NZ) {
    z_edge_body(srcE, dstE, si2, sj2, Zp, E, Etot,
                blockIdx.x * 256 + threadIdx.x, NZ * 256);
    return;
  }
  const int bid = blockIdx.x - NZ;
  const int p = bid & (HP - 1);
  const int g = bid >> 3;
  const int lo = p * hstep;
  const int tid = threadIdx.x;
  for (int i = tid; i < hstep; i += 256) {
    int node = lo + i;
    lcur[i] = (node < N) ? partial[(size_t)g * N + node] : 0;
  }
  __syncthreads();
  const int stride = HG * 256;
  int e = g * 256 + tid;
  for (; e + 3 * stride < E; e += 4 * stride) {
    int d0 = dstE[e] - lo;
    int d1 = dstE[e + stride] - lo;
    int d2 = dstE[e + 2 * stride] - lo;
    int d3 = dstE[e + 3 * stride] - lo;
    if ((unsigned)d0 < (unsigned)hstep) esrc[atomicAdd(&lcur[d0], 1)] = srcE[e];
    if ((unsigned)d1 < (unsigned)hstep) esrc[atomicAdd(&lcur[d1], 1)] = srcE[e + stride];
    if ((unsigned)d2 < (unsigned)hstep) esrc[atomicAdd(&lcur[d2], 1)] = srcE[e + 2 * stride];
    if ((unsigned)d3 < (unsigned)hstep) esrc[atomicAdd(&lcur[d3], 1)] = srcE[e + 3 * stride];
  }
  for (; e < E; e += stride) {
    int d = dstE[e] - lo;
    if ((unsigned)d < (unsigned)hstep) esrc[atomicAdd(&lcur[d], 1)] = srcE[e];
  }
}

// one wave per dst node (scalarized): inline attention weights, inline
// self-loop term, acc += w * hq[src], fused head-mean + bias (+relu)
__global__ __launch_bounds__(256) void csr_aggregate(
    const int* __restrict__ rowptr, const int* __restrict__ esrc,
    const unsigned* __restrict__ hq, const float2* __restrict__ si2,
    const float2* __restrict__ sj2, const float* __restrict__ Zp,
    const float* __restrict__ bias, float* __restrict__ out,
    int N, int do_relu) {
  int lane = threadIdx.x & 63;
  int wid = (blockIdx.x * blockDim.x + threadIdx.x) >> 6;
  int nw = (gridDim.x * blockDim.x) >> 6;
  float z0 = 1.f / (Zp[0] + 1e-10f);
  float z1 = 1.f / (Zp[1] + 1e-10f);
  float bv = bias[lane];
  for (int n0 = wid; n0 < N; n0 += nw) {
    // n is wave-uniform; force SGPR so the rowptr/esrc/sj2 chain is scalar
    int n = __builtin_amdgcn_readfirstlane(n0);
    int beg = rowptr[n], end = rowptr[n + 1];
    float2 siv = si2[n];
    // self-loop term (src = dst = n)
    float acc0, acc1;
    {
      float2 jv = sj2[n];
      unsigned p = hq[(size_t)n * 64 + lane];
      float a0 = siv.x + jv.x, a1 = siv.y + jv.y;
      a0 = a0 >= 0.f ? a0 : 0.2f * a0;
      a1 = a1 >= 0.f ? a1 : 0.2f * a1;
      acc0 = bflo(p) * __expf(a0);
      acc1 = bfhi(p) * __expf(a1);
    }
    int k = beg;
    for (; k + 4 <= end; k += 4) {
      int s0 = esrc[k], s1 = esrc[k + 1], s2 = esrc[k + 2], s3 = esrc[k + 3];
      float2 j0 = sj2[s0], j1 = sj2[s1], j2 = sj2[s2], j3 = sj2[s3];
      unsigned p0 = hq[(size_t)s0 * 64 + lane];
      unsigned p1 = hq[(size_t)s1 * 64 + lane];
      unsigned p2 = hq[(size_t)s2 * 64 + lane];
      unsigned p3 = hq[(size_t)s3 * 64 + lane];
      float a00 = siv.x + j0.x, a01 = siv.y + j0.y;
      float a10 = siv.x + j1.x, a11 = siv.y + j1.y;
      float a20 = siv.x + j2.x, a21 = siv.y + j2.y;
      float a30 = siv.x + j3.x, a31 = siv.y + j3.y;
      a00 = a00 >= 0.f ? a00 : 0.2f * a00;  a01 = a01 >= 0.f ? a01 : 0.2f * a01;
      a10 = a10 >= 0.f ? a10 : 0.2f * a10;  a11 = a11 >= 0.f ? a11 : 0.2f * a11;
      a20 = a20 >= 0.f ? a20 : 0.2f * a20;  a21 = a21 >= 0.f ? a21 : 0.2f * a21;
      a30 = a30 >= 0.f ? a30 : 0.2f * a30;  a31 = a31 >= 0.f ? a31 : 0.2f * a31;
      float w00 = __expf(a00), w01 = __expf(a01);
      float w10 = __expf(a10), w11 = __expf(a11);
      float w20 = __expf(a20), w21 = __expf(a21);
      float w30 = __expf(a30), w31 = __expf(a31);
      acc0 += bflo(p0) * w00 + bflo(p1) * w10 + bflo(p2) * w20 + bflo(p3) * w30;
      acc1 += bfhi(p0) * w01 + bfhi(p1) * w11 + bfhi(p2) * w21 + bfhi(p3) * w31;
    }
    for (; k < end; ++k) {
      int s = esrc[k];
      float2 jv = sj2[s];
      unsigned p = hq[(size_t)s * 64 + lane];
      float a0 = siv.x + jv.x, a1 = siv.y + jv.y;
      a0 = a0 >= 0.f ? a0 : 0.2f * a0;
      a1 = a1 >= 0.f ? a1 : 0.2f * a1;
      acc0 += bflo(p) * __expf(a0);
      acc1 += bfhi(p) * __expf(a1);
    }
    float r = 0.5f * (acc0 * z0 + acc1 * z1) + bv;
    if (do_relu) r = fmaxf(r, 0.f);
    out[(size_t)n * 64 + lane] = r;
  }
}

extern "C" void kernel_launch(void* const* d_in, const int* in_sizes, int n_in,
                              void* d_out, int out_size, void* d_ws, size_t ws_size,
                              hipStream_t stream) {
  const float* x    = (const float*)d_in[0];
  const int*   ei   = (const int*)d_in[1];   // [2, E] int32
  const float* W1   = (const float*)d_in[2];
  const float* att1 = (const float*)d_in[3];
  const float* b1   = (const float*)d_in[4];
  const float* W2   = (const float*)d_in[5];
  const float* att2 = (const float*)d_in[6];
  const float* b2   = (const float*)d_in[7];
  float* out = (float*)d_out;

  const int N = in_sizes[0] / 128;   // 50000
  const int E = in_sizes[1] / 2;     // 800000
  const int Etot = E + N;            // incl. self-loops (Z sums only)
  const int* srcE = ei;
  const int* dstE = ei + E;

  // workspace layout (16B-sensitive arrays aligned)
  unsigned* hq = (unsigned*)d_ws;                 // N*64 packed bf16x2
  float* si    = (float*)(hq + (size_t)N * 64);   // N*2
  float* sj    = si + (size_t)N * 2;              // N*2
  float* Z     = sj + (size_t)N * 2;              // 4 (L1: Z[0..1], L2: Z[2..3])
  float* x2    = Z + 4;                           // N*64  (overlays partial)
  int* partial = (int*)x2;                        // HG*N  (dies before x2 born)
  int* rowptr  = (int*)(x2 + (size_t)N * 64);     // N+1
  int* deg     = rowptr + (N + 1);                // N
  int* esrc    = deg + N;                         // E (real edges only)
  int* bsum    = esrc + E;                        // up to 256
  uintptr_t wp = ((uintptr_t)(bsum + 256) + 15) & ~(uintptr_t)15;
  unsigned short* wbf1 = (unsigned short*)wp;     // 128*128 bf16 W1
  unsigned short* wbf2 = wbf1 + 128 * 128;        // 128*64 bf16 W2

  dim3 blk(256);
  int nb = (N + 1023) / 1024;
  int ntiles = (N + 63) / 64;
  int hstep = (N + HP - 1) / HP;  // 6250 <= HRANGE_MAX

  // 0) W -> bf16 + zero Z
  init_ws<<<64, blk, 0, stream>>>(W1, W2, wbf1, wbf2, Z);
  // 1) hist (blocks[0,512), atomic-free) + gemm1 (MFMA, LDS-staged bf16 W)
  gemm_mfma<128><<<NHISTB + ntiles, blk, 0, stream>>>(
      x, wbf1, att1, hq, si, sj, N, dstE, partial, E, NHISTB, hstep);
  // 2) deg = sum of stripe partials (wide-parallel)
  reduce_deg<<<256, blk, 0, stream>>>(partial, deg, N);
  // 3,4) rowptr prefix + per-stripe exclusive offsets
  scan_blocks<<<nb, blk, 0, stream>>>(deg, rowptr, bsum, N);
  scan_finish<<<256, blk, 0, stream>>>(rowptr, bsum, partial, N, E, nb);
  // 5) z1 (first 256 blocks, co-scheduled) + atomic-free scatter (512 blocks)
  scatter_z<<<NZ + NHISTB, blk, 0, stream>>>(
      srcE, dstE, partial, esrc, (const float2*)si, (const float2*)sj,
      Z, E, Etot, hstep, N);
  // 6) layer-1 aggregation -> x2 (self-loop inline; relu fused)
  csr_aggregate<<<4096, blk, 0, stream>>>(rowptr, esrc, hq, (const float2*)si,
                                          (const float2*)sj, Z, b1, x2, N, 1);
  // 7) gemm2 (MFMA, nhistb=0: hist branch never taken)
  gemm_mfma<64><<<ntiles, blk, 0, stream>>>(
      x2, wbf2, att2, hq, si, sj, N, dstE, partial, E, 0, hstep);
  // 8) z2
  z_edge<<<NZ, blk, 0, stream>>>(srcE, dstE, (const float2*)si,
                                 (const float2*)sj, Z + 2, E, Etot);
  // 9) layer-2 aggregation -> out
  csr_aggregate<<<4096, blk, 0, stream>>>(rowptr, esrc, hq, (const float2*)si,
                                          (const float2*)sj, Z + 2, b2, out, N, 0);
}